// Round 15
// baseline (405.329 us; speedup 1.0000x reference)
//
#include <hip/hip_runtime.h>
#include <hip/hip_bf16.h>

// DigitCaps, fp32 in / fp32 out:
//   u [16,1152,8], W [10,1152,16,8], Bp [10,1,1152], out [16,10,16]
// Exact algebra: A_sum[b,d,m] = dot(T[b,d,:], U_hat[b,d,m,:])/sqrt8,
//   T = sum_n U_hat;  C = softmax_d;  S = sum_n (Bp+C)*U_hat;  squash(S).
// Evidence r8/r10/r13: dur ~= 84 us regardless of kernel internals at 4
// dispatches -> per-dispatch fixed cost ~15-20 us dominates. r14: spinning
// grid barriers cost ~90 us each (agent-scope acquire poll thrash) — NEVER
// spin. r12: last-arrival ticket (fence+atomic+fence, no waiting) is correct.
// Round 15: 3 dispatches. K1 = partials + two-level last-arrival reduce -> T.
// K2 = softmax/S partials + same reduce + fused squash. Tiny memset zeroes
// the 75 ticket counters.
constexpr int BN = 16, NN = 1152, DP = 8, ND = 10, DD = 16;
constexpr int NCH = 2;                   // n's per block
constexpr int NBLK = NN / NCH;           // 576 blocks
constexpr int CELLS = BN * ND * DD;      // 2560; cell = d*256 + b*16 + j
constexpr int GRP = 16;                  // blocks per ticket group
constexpr int NGRP = NBLK / GRP;         // 36 groups
constexpr int WCH = NCH * ND;            // 20 staged W chunks

__device__ __forceinline__ void stageWu(const float* __restrict__ u,
                                        const float* __restrict__ W,
                                        float* __restrict__ Wl,
                                        float* __restrict__ ul,
                                        int n0, int t) {
    for (int g = t; g < WCH * 32; g += 256) {
        const int c = g >> 5, w = g & 31;
        const int nn = c / ND, d = c - nn * ND;
        reinterpret_cast<float4*>(Wl)[g] =
            *reinterpret_cast<const float4*>(
                W + ((size_t)d * NN + (n0 + nn)) * (DD * DP) + w * 4);
    }
    if (t < BN * NCH * 2) {
        const int bb = t >> 2, r = t & 3, nn = r >> 1, half = r & 1;
        reinterpret_cast<float4*>(ul)[t] =
            *reinterpret_cast<const float4*>(
                u + ((size_t)bb * NN + (n0 + nn)) * DP + half * 4);
    }
}

// Reduce GRP partials of group g into dst (one block, 10 cells/thread).
__device__ __forceinline__ void reduce_group(const float* __restrict__ P,
                                             float* __restrict__ dst,
                                             int g, int t) {
#pragma unroll
    for (int d = 0; d < ND; ++d) {
        const int cell = d * 256 + t;
        float s0 = 0.f, s1 = 0.f, s2 = 0.f, s3 = 0.f;
#pragma unroll
        for (int p = 0; p < GRP; p += 4) {        // 16 independent loads
            s0 += P[(size_t)(g * GRP + p + 0) * CELLS + cell];
            s1 += P[(size_t)(g * GRP + p + 1) * CELLS + cell];
            s2 += P[(size_t)(g * GRP + p + 2) * CELLS + cell];
            s3 += P[(size_t)(g * GRP + p + 3) * CELLS + cell];
        }
        dst[(size_t)g * CELLS + cell] = (s0 + s1) + (s2 + s3);
    }
}

// ---- K1: stage W/u, partial T, two-level last-arrival reduction -> T ----
__global__ __launch_bounds__(256) void caps_T(
    const float* __restrict__ u, const float* __restrict__ W,
    float* __restrict__ Tp, float* __restrict__ Tg, float* __restrict__ T,
    unsigned* __restrict__ cnt)
{
    __shared__ float Wl[WCH * 128];      // 10 KB
    __shared__ float ul[BN * NCH * DP];  // 1 KB
    __shared__ unsigned tk1, tk2;
    const int blk = blockIdx.x, t = threadIdx.x, j = t & 15, b = t >> 4;
    const int n0 = blk * NCH;

    stageWu(u, W, Wl, ul, n0, t);
    __syncthreads();

    float Tacc[ND];
#pragma unroll
    for (int d = 0; d < ND; ++d) Tacc[d] = 0.f;
#pragma unroll
    for (int nn = 0; nn < NCH; ++nn) {
        const float4 u0 = reinterpret_cast<const float4*>(ul)[b * 4 + nn * 2];
        const float4 u1 = reinterpret_cast<const float4*>(ul)[b * 4 + nn * 2 + 1];
#pragma unroll
        for (int d = 0; d < ND; ++d) {
            const float4* wp =
                reinterpret_cast<const float4*>(Wl) + (nn * ND + d) * 32 + j * 2;
            const float4 w0 = wp[0], w1 = wp[1];
            Tacc[d] += w0.x * u0.x + w0.y * u0.y + w0.z * u0.z + w0.w * u0.w
                     + w1.x * u1.x + w1.y * u1.y + w1.z * u1.z + w1.w * u1.w;
        }
    }
    {
        float* dst = Tp + (size_t)blk * CELLS;
#pragma unroll
        for (int d = 0; d < ND; ++d) dst[d * 256 + t] = Tacc[d];
    }

    // level-1 ticket: last arrival in group reduces the group's 16 partials
    __threadfence();                     // release our Tp stores
    if (t == 0) tk1 = __hip_atomic_fetch_add(&cnt[blk / GRP], 1u,
                          __ATOMIC_ACQ_REL, __HIP_MEMORY_SCOPE_AGENT);
    __syncthreads();
    if (tk1 == GRP - 1) {
        __threadfence();                 // acquire group partials
        reduce_group(Tp, Tg, blk / GRP, t);
        // level-2: last of the 36 leaders reduces Tg -> T
        __threadfence();
        if (t == 0) tk2 = __hip_atomic_fetch_add(&cnt[36], 1u,
                              __ATOMIC_ACQ_REL, __HIP_MEMORY_SCOPE_AGENT);
        __syncthreads();
        if (tk2 == NGRP - 1) {
            __threadfence();
#pragma unroll
            for (int d = 0; d < ND; ++d) {
                const int cell = d * 256 + t;
                float s0 = 0.f, s1 = 0.f, s2 = 0.f, s3 = 0.f;
#pragma unroll
                for (int p = 0; p < NGRP; p += 4) {   // 36 = 9x4 independent
                    s0 += Tg[(size_t)(p + 0) * CELLS + cell];
                    s1 += Tg[(size_t)(p + 1) * CELLS + cell];
                    s2 += Tg[(size_t)(p + 2) * CELLS + cell];
                    s3 += Tg[(size_t)(p + 3) * CELLS + cell];
                }
                T[cell] = (s0 + s1) + (s2 + s3);
            }
        }
    }
}

// ---- K2: stage W/u/T, softmax_d, partial S, reduce + fused squash ----
__global__ __launch_bounds__(256) void caps_S(
    const float* __restrict__ u, const float* __restrict__ W,
    const float* __restrict__ Bp, const float* __restrict__ T,
    float* __restrict__ Sp, float* __restrict__ Sg,
    float* __restrict__ out, unsigned* __restrict__ cnt)
{
    __shared__ float Wl[WCH * 128];      // 10 KB
    __shared__ float ul[BN * NCH * DP];  // 1 KB
    __shared__ float Tl[CELLS];          // 10 KB
    __shared__ unsigned tk1, tk2;
    const int blk = blockIdx.x, t = threadIdx.x, j = t & 15, b = t >> 4;
    const int n0 = blk * NCH;
    constexpr float RS8 = 0.35355339059327373f;   // 1/sqrt(8)

    stageWu(u, W, Wl, ul, n0, t);
    for (int g = t; g < CELLS; g += 256) Tl[g] = T[g];  // scalar: no conflicts
    __syncthreads();

    float Treg[ND];
#pragma unroll
    for (int q = 0; q < ND; ++q) Treg[q] = Tl[q * 256 + t];
    float Sacc[ND];
#pragma unroll
    for (int q = 0; q < ND; ++q) Sacc[q] = 0.f;

#pragma unroll
    for (int nn = 0; nn < NCH; ++nn) {
        const int n = n0 + nn;
        const float4 u0 = reinterpret_cast<const float4*>(ul)[b * 4 + nn * 2];
        const float4 u1 = reinterpret_cast<const float4*>(ul)[b * 4 + nn * 2 + 1];
        float uh[ND], a[ND];
#pragma unroll
        for (int q = 0; q < ND; ++q) {
            const float4* wp =
                reinterpret_cast<const float4*>(Wl) + (nn * ND + q) * 32 + j * 2;
            const float4 w0 = wp[0], w1 = wp[1];
            const float s =
                  w0.x * u0.x + w0.y * u0.y + w0.z * u0.z + w0.w * u0.w
                + w1.x * u1.x + w1.y * u1.y + w1.z * u1.z + w1.w * u1.w;
            uh[q] = s;
            float v = Treg[q] * s;               // butterfly over 16 j-lanes
            v += __shfl_xor(v, 8, 16);
            v += __shfl_xor(v, 4, 16);
            v += __shfl_xor(v, 2, 16);
            v += __shfl_xor(v, 1, 16);
            a[q] = v * RS8;
        }
        float m = a[0];
#pragma unroll
        for (int q = 1; q < ND; ++q) m = fmaxf(m, a[q]);
        float e[ND], se = 0.f;
#pragma unroll
        for (int q = 0; q < ND; ++q) { e[q] = expf(a[q] - m); se += e[q]; }
        const float inv_se = 1.f / se;
#pragma unroll
        for (int q = 0; q < ND; ++q)
            Sacc[q] += (Bp[q * NN + n] + e[q] * inv_se) * uh[q];
    }
    {
        float* dst = Sp + (size_t)blk * CELLS;
#pragma unroll
        for (int q = 0; q < ND; ++q) dst[q * 256 + t] = Sacc[q];
    }

    // two-level last-arrival reduction, final leader fuses squash + out
    __threadfence();
    if (t == 0) tk1 = __hip_atomic_fetch_add(&cnt[37 + blk / GRP], 1u,
                          __ATOMIC_ACQ_REL, __HIP_MEMORY_SCOPE_AGENT);
    __syncthreads();
    if (tk1 == GRP - 1) {
        __threadfence();
        reduce_group(Sp, Sg, blk / GRP, t);
        __threadfence();
        if (t == 0) tk2 = __hip_atomic_fetch_add(&cnt[74], 1u,
                              __ATOMIC_ACQ_REL, __HIP_MEMORY_SCOPE_AGENT);
        __syncthreads();
        if (tk2 == NGRP - 1) {
            __threadfence();
#pragma unroll
            for (int d = 0; d < ND; ++d) {
                const int cell = d * 256 + t;
                float s0 = 0.f, s1 = 0.f, s2 = 0.f, s3 = 0.f;
#pragma unroll
                for (int p = 0; p < NGRP; p += 4) {
                    s0 += Sg[(size_t)(p + 0) * CELLS + cell];
                    s1 += Sg[(size_t)(p + 1) * CELLS + cell];
                    s2 += Sg[(size_t)(p + 2) * CELLS + cell];
                    s3 += Sg[(size_t)(p + 3) * CELLS + cell];
                }
                const float Sv = (s0 + s1) + (s2 + s3);
                float n2 = Sv * Sv;              // t = b*16+j, 16-aligned
#pragma unroll
                for (int off = 8; off >= 1; off >>= 1)
                    n2 += __shfl_xor(n2, off, 16);
                const float nrm = sqrtf(n2);
                const float coef = 1.f - 1.f / (expf(nrm) + 1e-7f);
                out[((size_t)b * ND + d) * DD + j] = Sv * (coef / (nrm + 1e-7f));
            }
        }
    }
}

extern "C" void kernel_launch(void* const* d_in, const int* in_sizes, int n_in,
                              void* d_out, int out_size, void* d_ws, size_t ws_size,
                              hipStream_t stream) {
    const float* u  = nullptr;   // 147456
    const float* W  = nullptr;   // 1474560
    const float* Bp = nullptr;   // 11520
    for (int i = 0; i < n_in; ++i) {
        const int s = in_sizes[i];
        if (s == BN * NN * DP)            u  = (const float*)d_in[i];
        else if (s == ND * NN * DD * DP)  W  = (const float*)d_in[i];
        else if (s == ND * NN)            Bp = (const float*)d_in[i];
    }
    float* out = (float*)d_out;
    unsigned* cnt = (unsigned*)d_ws;              // 75 ticket counters
    float* base = (float*)d_ws + 128;             // 512B-aligned data region
    float* Tp = base;                             // 576*2560
    float* Tg = Tp + (size_t)NBLK * CELLS;        // 36*2560
    float* T  = Tg + (size_t)NGRP * CELLS;        // 2560
    float* Sp = T + CELLS;                        // 576*2560
    float* Sg = Sp + (size_t)NBLK * CELLS;        // 36*2560

    hipMemsetAsync(d_ws, 0, 128 * sizeof(float), stream);  // zero counters
    caps_T<<<dim3(NBLK), 256, 0, stream>>>(u, W, Tp, Tg, T, cnt);
    caps_S<<<dim3(NBLK), 256, 0, stream>>>(u, W, Bp, T, Sp, Sg, out, cnt);
}

// Round 16
// 83.032 us; speedup vs baseline: 4.8816x; 4.8816x over previous
//
#include <hip/hip_runtime.h>
#include <hip/hip_bf16.h>

// DigitCaps, fp32 in / fp32 out:
//   u [16,1152,8], W [10,1152,16,8], Bp [10,1,1152], out [16,10,16]
// Exact algebra: A_sum[b,d,m] = dot(T[b,d,:], U_hat[b,d,m,:])/sqrt8,
//   T = sum_n U_hat;  C = softmax_d;  S = sum_n (Bp+C)*U_hat;  squash(S).
// Measured laws so far:
//  - r14: spinning grid barriers ~90us each. NEVER spin.
//  - r15: block-level device fences + bulk dirty plain stores -> L2 writeback
//    storms (~150us/kernel). Publish bulk data ONLY via kernel boundaries.
//  - r12: fp32 atomicAdd is EA write-through (ok for small totals only).
//  - r7/r12: >10-deep serial VMEM chains at low occupancy = death; stage via
//    LDS with independent loads.
// Round 16: r13's safe 4-dispatch skeleton, every kernel redesigned for
// <=5us: 288 blocks x 4 n (all CUs), 2.95MB partials, staged W/u/Bp/T.
constexpr int BN = 16, NN = 1152, DP = 8, ND = 10, DD = 16;
constexpr int NCH = 4;                   // n's per phase block
constexpr int NBLK = NN / NCH;           // 288 blocks
constexpr int CELLS = BN * ND * DD;      // 2560; cell = d*256 + b*16 + j
constexpr int RL = 16;                   // reduction lanes per cell
constexpr int WCH = NCH * ND;            // 40 staged W chunks (512B each)

// Stage this block's W slice (40 chunks x 128 floats = 20KB) + u (2KB).
__device__ __forceinline__ void stageWu(const float* __restrict__ u,
                                        const float* __restrict__ W,
                                        float* __restrict__ Wl,
                                        float* __restrict__ ul,
                                        int n0, int t) {
#pragma unroll
    for (int g = t; g < WCH * 32; g += 256) {   // 5 independent float4 loads
        const int c = g >> 5, w = g & 31;
        const int nn = c / ND, d = c - nn * ND;
        reinterpret_cast<float4*>(Wl)[g] =
            *reinterpret_cast<const float4*>(
                W + ((size_t)d * NN + (n0 + nn)) * (DD * DP) + w * 4);
    }
    if (t < BN * NCH * 2) {                     // 128 float4s
        const int bb = t >> 3, r = t & 7, nn = r >> 1, half = r & 1;
        reinterpret_cast<float4*>(ul)[t] =
            *reinterpret_cast<const float4*>(
                u + ((size_t)bb * NN + (n0 + nn)) * DP + half * 4);
    }
}

// ---- K1: partial T over 4 n's; plain coalesced stores ----
__global__ __launch_bounds__(256) void caps_T(
    const float* __restrict__ u, const float* __restrict__ W,
    float* __restrict__ Tp)
{
    __shared__ float Wl[WCH * 128];      // 20 KB
    __shared__ float ul[BN * NCH * DP];  // 2 KB
    const int t = threadIdx.x, j = t & 15, b = t >> 4;
    const int n0 = blockIdx.x * NCH;

    stageWu(u, W, Wl, ul, n0, t);
    __syncthreads();

    float Tacc[ND];
#pragma unroll
    for (int d = 0; d < ND; ++d) Tacc[d] = 0.f;
#pragma unroll
    for (int nn = 0; nn < NCH; ++nn) {
        const float4 u0 = reinterpret_cast<const float4*>(ul)[(b * NCH + nn) * 2];
        const float4 u1 = reinterpret_cast<const float4*>(ul)[(b * NCH + nn) * 2 + 1];
#pragma unroll
        for (int d = 0; d < ND; ++d) {
            const float4* wp =
                reinterpret_cast<const float4*>(Wl) + (nn * ND + d) * 32 + j * 2;
            const float4 w0 = wp[0], w1 = wp[1];
            Tacc[d] += w0.x * u0.x + w0.y * u0.y + w0.z * u0.z + w0.w * u0.w
                     + w1.x * u1.x + w1.y * u1.y + w1.z * u1.z + w1.w * u1.w;
        }
    }
    float* dst = Tp + (size_t)blockIdx.x * CELLS;
#pragma unroll
    for (int d = 0; d < ND; ++d) dst[d * 256 + t] = Tacc[d];   // 1 KB runs
}

// ---- K2: reduce Tp[288][2560] -> T[2560]; 160 blocks, 18 indep loads ----
__global__ __launch_bounds__(256) void reduce_T(
    const float* __restrict__ Tp, float* __restrict__ T)
{
    __shared__ float red[256];
    const int t = threadIdx.x;
    const int cell = blockIdx.x * RL + (t & 15);
    const int cc = t >> 4;
    float s0 = 0.f, s1 = 0.f;
#pragma unroll
    for (int k = 0; k < NBLK / RL; k += 2) {       // 18 independent loads
        s0 += Tp[(size_t)(cc + RL * (k + 0)) * CELLS + cell];
        s1 += Tp[(size_t)(cc + RL * (k + 1)) * CELLS + cell];
    }
    red[t] = s0 + s1;
    __syncthreads();
    if (t < RL) {
        float acc = 0.f;
#pragma unroll
        for (int g = 0; g < RL; ++g) acc += red[t + RL * g];
        T[blockIdx.x * RL + t] = acc;
    }
}

// ---- K3: scores -> softmax_d -> partial S; W/u/Bp/T all LDS-staged ----
__global__ __launch_bounds__(256) void caps_S(
    const float* __restrict__ u, const float* __restrict__ W,
    const float* __restrict__ Bp, const float* __restrict__ T,
    float* __restrict__ Sp)
{
    __shared__ float Wl[WCH * 128];      // 20 KB
    __shared__ float ul[BN * NCH * DP];  // 2 KB
    __shared__ float Tl[CELLS];          // 10 KB
    __shared__ float Bpl[ND * NCH];      // 40 floats
    const int t = threadIdx.x, j = t & 15, b = t >> 4;
    const int n0 = blockIdx.x * NCH;
    constexpr float RS8 = 0.35355339059327373f;    // 1/sqrt(8)

    stageWu(u, W, Wl, ul, n0, t);
#pragma unroll
    for (int g = t; g < CELLS / 4; g += 256)       // 640 float4s: T
        reinterpret_cast<float4*>(Tl)[g] = reinterpret_cast<const float4*>(T)[g];
    if (t < ND)                                    // Bp: 10 float4s (n0%4==0)
        reinterpret_cast<float4*>(Bpl)[t] =
            *reinterpret_cast<const float4*>(Bp + t * NN + n0);
    __syncthreads();

    float Treg[ND];
#pragma unroll
    for (int q = 0; q < ND; ++q) Treg[q] = Tl[q * 256 + t];
    float Sacc[ND];
#pragma unroll
    for (int q = 0; q < ND; ++q) Sacc[q] = 0.f;

#pragma unroll
    for (int nn = 0; nn < NCH; ++nn) {
        const float4 u0 = reinterpret_cast<const float4*>(ul)[(b * NCH + nn) * 2];
        const float4 u1 = reinterpret_cast<const float4*>(ul)[(b * NCH + nn) * 2 + 1];
        float uh[ND], a[ND];
#pragma unroll
        for (int q = 0; q < ND; ++q) {
            const float4* wp =
                reinterpret_cast<const float4*>(Wl) + (nn * ND + q) * 32 + j * 2;
            const float4 w0 = wp[0], w1 = wp[1];
            const float s =
                  w0.x * u0.x + w0.y * u0.y + w0.z * u0.z + w0.w * u0.w
                + w1.x * u1.x + w1.y * u1.y + w1.z * u1.z + w1.w * u1.w;
            uh[q] = s;
            float v = Treg[q] * s;                 // butterfly over 16 j-lanes
            v += __shfl_xor(v, 8, 16);
            v += __shfl_xor(v, 4, 16);
            v += __shfl_xor(v, 2, 16);
            v += __shfl_xor(v, 1, 16);
            a[q] = v * RS8;
        }
        float m = a[0];
#pragma unroll
        for (int q = 1; q < ND; ++q) m = fmaxf(m, a[q]);
        float e[ND], se = 0.f;
#pragma unroll
        for (int q = 0; q < ND; ++q) { e[q] = expf(a[q] - m); se += e[q]; }
        const float inv_se = 1.f / se;
#pragma unroll
        for (int q = 0; q < ND; ++q)
            Sacc[q] += (Bpl[q * NCH + nn] + e[q] * inv_se) * uh[q];
    }
    float* dst = Sp + (size_t)blockIdx.x * CELLS;
#pragma unroll
    for (int q = 0; q < ND; ++q) dst[q * 256 + t] = Sacc[q];
}

// ---- K4: reduce Sp[288][2560] + fused squash; 160 blocks = (q,b) ----
__global__ __launch_bounds__(256) void reduce_S_out(
    const float* __restrict__ Sp, float* __restrict__ out)
{
    __shared__ float red[256];
    const int q = blockIdx.x >> 4, b = blockIdx.x & 15;
    const int t = threadIdx.x, j = t & 15, cc = t >> 4;
    const int cell = q * 256 + b * 16 + j;
    float s0 = 0.f, s1 = 0.f;
#pragma unroll
    for (int k = 0; k < NBLK / RL; k += 2) {       // 18 independent loads
        s0 += Sp[(size_t)(cc + RL * (k + 0)) * CELLS + cell];
        s1 += Sp[(size_t)(cc + RL * (k + 1)) * CELLS + cell];
    }
    red[t] = s0 + s1;
    __syncthreads();
    if (t < RL) {                                  // t = j
        float Sv = 0.f;
#pragma unroll
        for (int g = 0; g < RL; ++g) Sv += red[t + RL * g];
        float n2 = Sv * Sv;
#pragma unroll
        for (int off = 8; off >= 1; off >>= 1) n2 += __shfl_xor(n2, off, 16);
        const float nrm = sqrtf(n2);
        const float coef = 1.f - 1.f / (expf(nrm) + 1e-7f);
        out[((size_t)b * ND + q) * DD + t] = Sv * (coef / (nrm + 1e-7f));
    }
}

extern "C" void kernel_launch(void* const* d_in, const int* in_sizes, int n_in,
                              void* d_out, int out_size, void* d_ws, size_t ws_size,
                              hipStream_t stream) {
    const float* u  = nullptr;   // 147456
    const float* W  = nullptr;   // 1474560
    const float* Bp = nullptr;   // 11520
    for (int i = 0; i < n_in; ++i) {
        const int s = in_sizes[i];
        if (s == BN * NN * DP)            u  = (const float*)d_in[i];
        else if (s == ND * NN * DD * DP)  W  = (const float*)d_in[i];
        else if (s == ND * NN)            Bp = (const float*)d_in[i];
    }
    float* out = (float*)d_out;
    float* Tp = (float*)d_ws;                     // 288*2560 fp32 = 2.95 MB
    float* T  = Tp + (size_t)NBLK * CELLS;        // 2560 fp32
    float* Sp = T + CELLS;                        // 288*2560 fp32 = 2.95 MB
    // every ws word written before read -> poison harmless; no memset

    caps_T      <<<dim3(NBLK), 256, 0, stream>>>(u, W, Tp);
    reduce_T    <<<dim3(CELLS / RL), 256, 0, stream>>>(Tp, T);
    caps_S      <<<dim3(NBLK), 256, 0, stream>>>(u, W, Bp, T, Sp);
    reduce_S_out<<<dim3(ND * BN), 256, 0, stream>>>(Sp, out);
}